// Round 7
// baseline (1505.830 us; speedup 1.0000x reference)
//
#include <hip/hip_runtime.h>

#define NN 50000
#define NE 800000
#define FIN 128
#define HD 64
#define SL 3
#define GBM 782    // ceil(NN/64) row-tiles for MFMA kernels
#define NBIN 196   // ceil(NN/256) dst bins
#define BSH 8      // 256 nodes per bin
#define BND 256    // nodes per bin
#define ASTR 66    // LDS accumulator stride (floats) — spreads banks

typedef __attribute__((ext_vector_type(8))) short bf16x8;
typedef __attribute__((ext_vector_type(4))) float f32x4;
#define MFMA(A, B, C) __builtin_amdgcn_mfma_f32_16x16x32_bf16(A, B, C, 0, 0, 0)

// ---------------- bf16 pack helpers (RNE) ----------------

__device__ __forceinline__ unsigned int bfr(float x) {
    unsigned int u = __float_as_uint(x);
    return (u + 0x7fffu + ((u >> 16) & 1u)) >> 16;
}
__device__ __forceinline__ unsigned int bf2(float lo, float hi) {
    return bfr(lo) | (bfr(hi) << 16);
}

// ---------------- binned edge partition (no per-node CSR) ----------------

// per-block LDS histogram of dst>>8, one global atomicAdd per bin per block
__global__ __launch_bounds__(256) void binhist_k(const int* __restrict__ dst,
                                                 int* __restrict__ bincnt) {
    __shared__ int h[256];
    int t = threadIdx.x;
    h[t] = 0;
    __syncthreads();
    int base = blockIdx.x * 4096;
    for (int i = t; i < 4096; i += 256) {
        int e = base + i;
        if (e < NE) atomicAdd(&h[dst[e] >> BSH], 1);
    }
    __syncthreads();
    if (t < NBIN && h[t]) atomicAdd(&bincnt[t], h[t]);
}

// exclusive scan of 196 bin counts -> binoff (+ seed gbcur)
__global__ __launch_bounds__(256) void binscan_k(const int* __restrict__ bincnt,
                                                 int* __restrict__ binoff,
                                                 int* __restrict__ gbcur) {
    __shared__ int sh[256];
    int t = threadIdx.x;
    int v = (t < NBIN) ? bincnt[t] : 0;
    sh[t] = v;
    __syncthreads();
    for (int d = 1; d < 256; d <<= 1) {
        int u = (t >= d) ? sh[t - d] : 0;
        __syncthreads();
        sh[t] += u;
        __syncthreads();
    }
    if (t < NBIN) {
        int ex = sh[t] - v;
        binoff[t] = ex;
        gbcur[t] = ex;
    }
    if (t == 255) binoff[NBIN] = sh[255];
}

// partition edges into bin runs. packed: src (16b) | (dst & 255) << 16
__global__ __launch_bounds__(256) void binpass_k(const int* __restrict__ src,
                                                 const int* __restrict__ dst,
                                                 const float* __restrict__ attr,
                                                 int* __restrict__ gbcur,
                                                 int2* __restrict__ tedge) {
    __shared__ int cnt_lds[256], runbase[256], lcur[256];
    int t = threadIdx.x;
    cnt_lds[t] = 0;
    lcur[t] = 0;
    __syncthreads();
    int base = blockIdx.x * 4096;
    for (int i = t; i < 4096; i += 256) {
        int e = base + i;
        if (e < NE) atomicAdd(&cnt_lds[dst[e] >> BSH], 1);
    }
    __syncthreads();
    if (t < NBIN && cnt_lds[t]) runbase[t] = atomicAdd(&gbcur[t], cnt_lds[t]);
    __syncthreads();
    for (int i = t; i < 4096; i += 256) {
        int e = base + i;
        if (e < NE) {
            int d = dst[e];
            int b = d >> BSH;
            int r = atomicAdd(&lcur[b], 1);
            tedge[runbase[b] + r] =
                make_int2(src[e] | ((d & 255) << 16), __float_as_int(attr[e]));
        }
    }
}

// ---------------- binned scatter: LDS fp32 accumulate, bf16 writeback ----------------
// one block per 256-node bin; 8 lanes per edge (uint4 gather = 8 bf16 feats);
// ds_add_f32 into acc[node*66 + feat]; coalesced bf16 store to mb.

__global__ __launch_bounds__(1024) void scatbin_k(const uint4* __restrict__ hb4,
                                                  const int* __restrict__ binoff,
                                                  const int2* __restrict__ tedge,
                                                  uint4* __restrict__ mb4) {
    __shared__ float acc[BND * ASTR];  // 67.6 KB
    int t = threadIdx.x;
    int b = blockIdx.x;
    for (int i = t; i < BND * ASTR; i += 1024) acc[i] = 0.f;
    __syncthreads();

    int s = binoff[b], e = binoff[b + 1];
    int f = t & 7;        // uint4 chunk within row (feats f*8 .. f*8+7)
    int g = t >> 3;       // edge slot 0..127
    for (int i = s + g; i < e; i += 128) {
        int2 ed = tedge[i];
        int srcn = ed.x & 0xffff;
        int dl   = (ed.x >> 16) & 0xff;
        float a  = __int_as_float(ed.y);
        uint4 hv = hb4[(size_t)srcn * 8 + f];
        float* ap = &acc[dl * ASTR + f * 8];
        atomicAdd(&ap[0], a * __uint_as_float(hv.x << 16));
        atomicAdd(&ap[1], a * __uint_as_float(hv.x & 0xffff0000u));
        atomicAdd(&ap[2], a * __uint_as_float(hv.y << 16));
        atomicAdd(&ap[3], a * __uint_as_float(hv.y & 0xffff0000u));
        atomicAdd(&ap[4], a * __uint_as_float(hv.z << 16));
        atomicAdd(&ap[5], a * __uint_as_float(hv.z & 0xffff0000u));
        atomicAdd(&ap[6], a * __uint_as_float(hv.w << 16));
        atomicAdd(&ap[7], a * __uint_as_float(hv.w & 0xffff0000u));
    }
    __syncthreads();

    // writeback: 2048 uint4 chunks, 2 per thread
#pragma unroll
    for (int it = 0; it < 2; it++) {
        int idx = t + it * 1024;
        int node = idx >> 3, c = idx & 7;
        int row = b * BND + node;
        if (row < NN) {
            const float* ap = &acc[node * ASTR + c * 8];
            uint4 o;
            o.x = bf2(ap[0], ap[1]);
            o.y = bf2(ap[2], ap[3]);
            o.z = bf2(ap[4], ap[5]);
            o.w = bf2(ap[6], ap[7]);
            mb4[(size_t)row * 8 + c] = o;
        }
    }
}

// ---------------- weight prep: swizzle into MFMA B-fragment order, bf16 ----------------

__global__ __launch_bounds__(256) void wprep_k(const float* __restrict__ W1,
                                               const float* __restrict__ W2,
                                               const float* __restrict__ linW,
                                               short* __restrict__ prep) {
    int i = blockIdx.x * 256 + threadIdx.x;
    if (i < 24576) {
        int mat = i >> 12;
        int o = i & 4095;
        int j = o & 7, l = (o >> 3) & 63, s = (o >> 9) & 1, t = o >> 10;
        int k = 32 * s + 8 * (l >> 4) + j;
        int n = 16 * t + (l & 15);
        const float* Wsrc = (mat & 1) ? W2 : W1;
        prep[i] = (short)bfr(Wsrc[(mat >> 1) * 4096 + k * 64 + n]);
    } else if (i < 32768) {
        int o = i - 24576;
        int j = o & 7, l = (o >> 3) & 63, s = (o >> 9) & 3, t = o >> 11;
        int k = 32 * s + 8 * (l >> 4) + j;
        int n = 16 * t + (l & 15);
        prep[i] = (short)bfr(linW[k * 64 + n]);
    }
}

// ---------------- MFMA conv core (one weight set) ----------------

__device__ __forceinline__ void conv_core(bf16x8 a0, bf16x8 a1,
                                          const bf16x8* __restrict__ w1f,
                                          const float* __restrict__ b1,
                                          const bf16x8* __restrict__ w2f,
                                          short* tw, int c, int q, int l,
                                          f32x4 oc[4]) {
    f32x4 acc[4];
#pragma unroll
    for (int t = 0; t < 4; t++) acc[t] = (f32x4){0.f, 0.f, 0.f, 0.f};
#pragma unroll
    for (int t = 0; t < 4; t++) {
        acc[t] = MFMA(a0, w1f[(t * 2 + 0) * 64 + l], acc[t]);
        acc[t] = MFMA(a1, w1f[(t * 2 + 1) * 64 + l], acc[t]);
    }
#pragma unroll
    for (int t = 0; t < 4; t++) {
        float bb = b1[16 * t + c];
#pragma unroll
        for (int rg = 0; rg < 4; rg++) {
            float v = fmaxf(acc[t][rg] + bb, 0.f);
            tw[(4 * q + rg) * 72 + 16 * t + c] = (short)bfr(v);
        }
    }
    __syncthreads();
    bf16x8 ta0 = *(const bf16x8*)&tw[c * 72 + 8 * q];
    bf16x8 ta1 = *(const bf16x8*)&tw[c * 72 + 32 + 8 * q];
#pragma unroll
    for (int t = 0; t < 4; t++) oc[t] = (f32x4){0.f, 0.f, 0.f, 0.f};
#pragma unroll
    for (int t = 0; t < 4; t++) {
        oc[t] = MFMA(ta0, w2f[(t * 2 + 0) * 64 + l], oc[t]);
        oc[t] = MFMA(ta1, w2f[(t * 2 + 1) * 64 + l], oc[t]);
    }
}

// ---------------- single conv: out = [hprev +] relu(m@W1+b1)@W2+b2 ----------------

template <bool ADD, bool WB>
__global__ __launch_bounds__(256) void convm_k(const unsigned int* __restrict__ mb,
                                               const short* __restrict__ w1p,
                                               const float* __restrict__ b1,
                                               const short* __restrict__ w2p,
                                               const float* __restrict__ b2,
                                               const float* __restrict__ hprev,
                                               float* __restrict__ out,
                                               unsigned int* __restrict__ hb) {
    __shared__ short tls[4][16 * 72];
    int wv = threadIdx.x >> 6, l = threadIdx.x & 63;
    int c = l & 15, q = l >> 4;
    int rbase = blockIdx.x * 64 + wv * 16;

    int ar = rbase + c;
    bool aok = ar < NN;
    uint4 v0 = make_uint4(0, 0, 0, 0), v1 = v0;
    if (aok) {
        const uint4* mp = (const uint4*)(mb + (size_t)ar * 32);
        v0 = mp[q];
        v1 = mp[4 + q];
    }
    bf16x8 a0 = *(bf16x8*)&v0, a1 = *(bf16x8*)&v1;

    f32x4 oc[4];
    conv_core(a0, a1, (const bf16x8*)w1p, b1, (const bf16x8*)w2p, tls[wv], c, q, l, oc);

#pragma unroll
    for (int t = 0; t < 4; t++) {
        float bb = b2[16 * t + c];
#pragma unroll
        for (int rg = 0; rg < 4; rg++) {
            int row = rbase + 4 * q + rg;
            if (row < NN) {
                float v = oc[t][rg] + bb;
                if constexpr (ADD) v += hprev[(size_t)row * 64 + 16 * t + c];
                out[(size_t)row * 64 + 16 * t + c] = v;
                if constexpr (WB) {
                    float o = __shfl_xor(v, 1);
                    if ((c & 1) == 0)
                        hb[(size_t)row * 32 + 8 * t + (c >> 1)] = bf2(v, o);
                }
            }
        }
    }
}

// ---------------- dual conv: outa = conv_a(m); outb = hprev + conv_b(m) (+bf16 WB) ----------------

__global__ __launch_bounds__(256) void conv2_k(const unsigned int* __restrict__ mb,
                                               const short* __restrict__ wa1,
                                               const float* __restrict__ ba1,
                                               const short* __restrict__ wa2,
                                               const float* __restrict__ ba2,
                                               const short* __restrict__ wb1,
                                               const float* __restrict__ bb1,
                                               const short* __restrict__ wb2,
                                               const float* __restrict__ bb2,
                                               const float* __restrict__ hprev,
                                               float* __restrict__ outa,
                                               float* __restrict__ outb,
                                               unsigned int* __restrict__ hb) {
    __shared__ short tls[4][16 * 72];
    int wv = threadIdx.x >> 6, l = threadIdx.x & 63;
    int c = l & 15, q = l >> 4;
    int rbase = blockIdx.x * 64 + wv * 16;

    int ar = rbase + c;
    bool aok = ar < NN;
    uint4 v0 = make_uint4(0, 0, 0, 0), v1 = v0;
    if (aok) {
        const uint4* mp = (const uint4*)(mb + (size_t)ar * 32);
        v0 = mp[q];
        v1 = mp[4 + q];
    }
    bf16x8 a0 = *(bf16x8*)&v0, a1 = *(bf16x8*)&v1;

    f32x4 oc[4];
    conv_core(a0, a1, (const bf16x8*)wa1, ba1, (const bf16x8*)wa2, tls[wv], c, q, l, oc);
#pragma unroll
    for (int t = 0; t < 4; t++) {
        float bb = ba2[16 * t + c];
#pragma unroll
        for (int rg = 0; rg < 4; rg++) {
            int row = rbase + 4 * q + rg;
            if (row < NN)
                outa[(size_t)row * 64 + 16 * t + c] = oc[t][rg] + bb;
        }
    }
    __syncthreads();  // tls reuse

    conv_core(a0, a1, (const bf16x8*)wb1, bb1, (const bf16x8*)wb2, tls[wv], c, q, l, oc);
#pragma unroll
    for (int t = 0; t < 4; t++) {
        float bb = bb2[16 * t + c];
#pragma unroll
        for (int rg = 0; rg < 4; rg++) {
            int row = rbase + 4 * q + rg;
            if (row < NN) {
                float v = oc[t][rg] + bb + hprev[(size_t)row * 64 + 16 * t + c];
                outb[(size_t)row * 64 + 16 * t + c] = v;
                float o = __shfl_xor(v, 1);
                if ((c & 1) == 0)
                    hb[(size_t)row * 32 + 8 * t + (c >> 1)] = bf2(v, o);
            }
        }
    }
}

// ---------------- MFMA input linear: h0 = x @ lin_W + lin_b (+ bf16 copy) ----------------

__global__ __launch_bounds__(256) void linm_k(const float* __restrict__ x,
                                              const short* __restrict__ wp,
                                              const float* __restrict__ b,
                                              float* __restrict__ h0,
                                              unsigned int* __restrict__ hb) {
    int wv = threadIdx.x >> 6, l = threadIdx.x & 63;
    int c = l & 15, q = l >> 4;
    int rbase = blockIdx.x * 64 + wv * 16;
    int ar = rbase + c;
    bool aok = ar < NN;

    bf16x8 af[4];
#pragma unroll
    for (int s = 0; s < 4; s++) {
        float4 p0 = make_float4(0, 0, 0, 0), p1 = p0;
        if (aok) {
            const float4* xp = (const float4*)(x + (size_t)ar * FIN + 32 * s + 8 * q);
            p0 = xp[0];
            p1 = xp[1];
        }
        bf16x8 t;
        t[0] = (short)bfr(p0.x); t[1] = (short)bfr(p0.y);
        t[2] = (short)bfr(p0.z); t[3] = (short)bfr(p0.w);
        t[4] = (short)bfr(p1.x); t[5] = (short)bfr(p1.y);
        t[6] = (short)bfr(p1.z); t[7] = (short)bfr(p1.w);
        af[s] = t;
    }

    const bf16x8* wf = (const bf16x8*)wp;
    f32x4 acc[4];
#pragma unroll
    for (int t = 0; t < 4; t++) acc[t] = (f32x4){0.f, 0.f, 0.f, 0.f};
#pragma unroll
    for (int t = 0; t < 4; t++)
#pragma unroll
        for (int s = 0; s < 4; s++)
            acc[t] = MFMA(af[s], wf[(t * 4 + s) * 64 + l], acc[t]);

#pragma unroll
    for (int t = 0; t < 4; t++) {
        float bb = b[16 * t + c];
#pragma unroll
        for (int rg = 0; rg < 4; rg++) {
            int row = rbase + 4 * q + rg;
            if (row < NN) {
                float v = acc[t][rg] + bb;
                h0[(size_t)row * 64 + 16 * t + c] = v;
                float o = __shfl_xor(v, 1);
                if ((c & 1) == 0)
                    hb[(size_t)row * 32 + 8 * t + (c >> 1)] = bf2(v, o);
            }
        }
    }
}

// ---------------- launch ----------------

extern "C" void kernel_launch(void* const* d_in, const int* in_sizes, int n_in,
                              void* d_out, int out_size, void* d_ws, size_t ws_size,
                              hipStream_t stream) {
    (void)in_sizes; (void)n_in; (void)out_size; (void)ws_size;

    const float* x    = (const float*)d_in[0];
    const int*   ei   = (const int*)d_in[1];
    const float* attr = (const float*)d_in[2];
    const float* linW = (const float*)d_in[3];
    const float* linb = (const float*)d_in[4];
    const float* W1   = (const float*)d_in[5];
    const float* b1   = (const float*)d_in[6];
    const float* W2   = (const float*)d_in[7];
    const float* b2   = (const float*)d_in[8];
    float* out = (float*)d_out;

    // workspace (16B alignment at each boundary)
    float*        h0    = (float*)d_ws;                          // NN*64 f32
    unsigned int* mb    = (unsigned int*)(h0 + (size_t)NN * HD); // NN*32 (bf16 m)
    unsigned int* hb    = mb + (size_t)NN * 32;                  // NN*32 (bf16 h)
    int2*         tedge = (int2*)(hb + (size_t)NN * 32);         // NE (bin-partitioned edges)
    short*        prep  = (short*)(tedge + NE);                  // 32768 shorts
    int*          bincnt= (int*)(prep + 32768);                  // 256
    int*          binoff= bincnt + 256;                          // 256+1
    int*          gbcur = binoff + 257;                          // 256

    const int* src = ei;
    const int* dst = ei + NE;

    float* scats = out;
    float* outs  = out + (size_t)SL * NN * HD;

    const size_t NH = (size_t)NN * HD;

    const short* w1p0 = prep;            // layer i: prep + i*8192
    const short* w2p0 = prep + 4096;
    const short* linp = prep + 24576;

    // binned edge partition (no per-node CSR)
    hipMemsetAsync(bincnt, 0, 256 * sizeof(int), stream);
    binhist_k<<<196, 256, 0, stream>>>(dst, bincnt);
    binscan_k<<<1, 256, 0, stream>>>(bincnt, binoff, gbcur);
    binpass_k<<<196, 256, 0, stream>>>(src, dst, attr, gbcur, tedge);
    wprep_k<<<128, 256, 0, stream>>>(W1, W2, linW, prep);

    // h0 = x @ lin_W + lin_b (+ bf16 into hb)
    linm_k<<<GBM, 256, 0, stream>>>(x, linp, linb, h0, hb);

    // layer 0
    scatbin_k<<<NBIN, 1024, 0, stream>>>((const uint4*)hb, binoff, tedge, (uint4*)mb);
    convm_k<true, true><<<GBM, 256, 0, stream>>>(mb, w1p0, b1, w2p0, b2, h0, outs, hb);

    // scatter(outs0): scats0 (W0) + outs1 (W1) fused
    scatbin_k<<<NBIN, 1024, 0, stream>>>((const uint4*)hb, binoff, tedge, (uint4*)mb);
    conv2_k<<<GBM, 256, 0, stream>>>(mb, w1p0, b1, w2p0, b2,
                                     w1p0 + 8192, b1 + 64, w2p0 + 8192, b2 + 64,
                                     outs, scats, outs + NH, hb);

    // scatter(outs1): scats1 (W1) + outs2 (W2) fused
    scatbin_k<<<NBIN, 1024, 0, stream>>>((const uint4*)hb, binoff, tedge, (uint4*)mb);
    conv2_k<<<GBM, 256, 0, stream>>>(mb, w1p0 + 8192, b1 + 64, w2p0 + 8192, b2 + 64,
                                     w1p0 + 16384, b1 + 128, w2p0 + 16384, b2 + 128,
                                     outs + NH, scats + NH, outs + 2 * NH, hb);

    // scatter(outs2): scats2 (W2)
    scatbin_k<<<NBIN, 1024, 0, stream>>>((const uint4*)hb, binoff, tedge, (uint4*)mb);
    convm_k<false, false><<<GBM, 256, 0, stream>>>(mb, w1p0 + 16384, b1 + 128,
                                                   w2p0 + 16384, b2 + 128,
                                                   nullptr, scats + 2 * NH, nullptr);
}

// Round 9
// 306.658 us; speedup vs baseline: 4.9105x; 4.9105x over previous
//
#include <hip/hip_runtime.h>

#define NN 50000
#define NE 800000
#define FIN 128
#define HD 64
#define SL 3
#define NBL 196   // ceil(NN/256)
#define GBM 782   // ceil(NN/64) row-tiles for MFMA kernels
#define NB  196   // dst bins (256 nodes each)
#define BSH 8     // bin shift

typedef __attribute__((ext_vector_type(8))) short bf16x8;
typedef __attribute__((ext_vector_type(4))) float f32x4;
#define MFMA(A, B, C) __builtin_amdgcn_mfma_f32_16x16x32_bf16(A, B, C, 0, 0, 0)

// ---------------- bf16 pack helpers (RNE) ----------------

__device__ __forceinline__ unsigned int bfr(float x) {
    unsigned int u = __float_as_uint(x);
    return (u + 0x7fffu + ((u >> 16) & 1u)) >> 16;
}
__device__ __forceinline__ unsigned int bf2(float lo, float hi) {
    return bfr(lo) | (bfr(hi) << 16);
}

// ---------------- per-node CSR build ----------------

__global__ void hist_k(const int* __restrict__ dst, int* __restrict__ cnt) {
    int e = blockIdx.x * blockDim.x + threadIdx.x;
    if (e < NE) atomicAdd(&cnt[dst[e]], 1);
}

__global__ __launch_bounds__(256) void partial_k(const int* __restrict__ cnt,
                                                 int* __restrict__ partials) {
    __shared__ int sh[256];
    int t = threadIdx.x;
    int idx = blockIdx.x * 256 + t;
    sh[t] = (idx < NN) ? cnt[idx] : 0;
    __syncthreads();
    for (int d = 128; d > 0; d >>= 1) {
        if (t < d) sh[t] += sh[t + d];
        __syncthreads();
    }
    if (t == 0) partials[blockIdx.x] = sh[0];
}

__global__ __launch_bounds__(256) void scanp_k(const int* __restrict__ partials,
                                               int* __restrict__ pscan,
                                               int* __restrict__ off) {
    __shared__ int sh[256];
    int t = threadIdx.x;
    int v = (t < NBL) ? partials[t] : 0;
    sh[t] = v;
    __syncthreads();
    for (int d = 1; d < 256; d <<= 1) {
        int u = (t >= d) ? sh[t - d] : 0;
        __syncthreads();
        sh[t] += u;
        __syncthreads();
    }
    if (t < NBL) pscan[t] = sh[t] - v;
    if (t == 255) off[NN] = sh[255];
}

__global__ __launch_bounds__(256) void offs_k(const int* __restrict__ cnt,
                                              const int* __restrict__ pscan,
                                              int* __restrict__ off,
                                              int* __restrict__ cur) {
    __shared__ int sh[256];
    int t = threadIdx.x;
    int idx = blockIdx.x * 256 + t;
    int v = (idx < NN) ? cnt[idx] : 0;
    sh[t] = v;
    __syncthreads();
    for (int d = 1; d < 256; d <<= 1) {
        int u = (t >= d) ? sh[t - d] : 0;
        __syncthreads();
        sh[t] += u;
        __syncthreads();
    }
    if (idx < NN) {
        int o = pscan[blockIdx.x] + sh[t] - v;
        off[idx] = o;
        cur[idx] = o;
    }
}

__global__ void gbininit_k(const int* __restrict__ off, int* __restrict__ gbin_cur) {
    int t = threadIdx.x;
    if (t < NB) gbin_cur[t] = off[t << BSH];
}

// phase A: partition edges into 196 dst-bins (contiguous per-block runs).
// packed: src (16b) | (dst & 255) << 16
__global__ __launch_bounds__(256) void binpass_k(const int* __restrict__ src,
                                                 const int* __restrict__ dst,
                                                 const float* __restrict__ attr,
                                                 int* __restrict__ gbin_cur,
                                                 int2* __restrict__ tedge) {
    __shared__ int cnt_lds[256], runbase[256], lcur[256];
    int t = threadIdx.x;
    cnt_lds[t] = 0;
    lcur[t] = 0;
    __syncthreads();
    int base = blockIdx.x * 4096;
    for (int i = t; i < 4096; i += 256) {
        int e = base + i;
        if (e < NE) atomicAdd(&cnt_lds[dst[e] >> BSH], 1);
    }
    __syncthreads();
    if (t < NB && cnt_lds[t]) runbase[t] = atomicAdd(&gbin_cur[t], cnt_lds[t]);
    __syncthreads();
    for (int i = t; i < 4096; i += 256) {
        int e = base + i;
        if (e < NE) {
            int d = dst[e];
            int b = d >> BSH;
            int r = atomicAdd(&lcur[b], 1);
            tedge[runbase[b] + r] =
                make_int2(src[e] | ((d & 255) << 16), __float_as_int(attr[e]));
        }
    }
}

// phase B: one block per bin; node-sort within the bin's L2-resident CSR window.
__global__ __launch_bounds__(256) void sortbin_k(const int* __restrict__ off,
                                                 const int2* __restrict__ tedge,
                                                 int* __restrict__ cur,
                                                 int2* __restrict__ cedge) {
    int b = blockIdx.x;
    int s = off[b << BSH];
    int e = off[min((b + 1) << BSH, NN)];
    for (int i = s + (int)threadIdx.x; i < e; i += 256) {
        int2 ed = tedge[i];
        int d = (b << BSH) | ((unsigned)ed.x >> 16);
        int p = atomicAdd(&cur[d], 1);
        cedge[p] = make_int2(ed.x & 0xffff, ed.y);
    }
}

// ---------------- weight prep: swizzle into MFMA B-fragment order, bf16 ----------------

__global__ __launch_bounds__(256) void wprep_k(const float* __restrict__ W1,
                                               const float* __restrict__ W2,
                                               const float* __restrict__ linW,
                                               short* __restrict__ prep) {
    int i = blockIdx.x * 256 + threadIdx.x;
    if (i < 24576) {
        int mat = i >> 12;
        int o = i & 4095;
        int j = o & 7, l = (o >> 3) & 63, s = (o >> 9) & 1, t = o >> 10;
        int k = 32 * s + 8 * (l >> 4) + j;
        int n = 16 * t + (l & 15);
        const float* Wsrc = (mat & 1) ? W2 : W1;
        prep[i] = (short)bfr(Wsrc[(mat >> 1) * 4096 + k * 64 + n]);
    } else if (i < 32768) {
        int o = i - 24576;
        int j = o & 7, l = (o >> 3) & 63, s = (o >> 9) & 3, t = o >> 11;
        int k = 32 * s + 8 * (l >> 4) + j;
        int n = 16 * t + (l & 15);
        prep[i] = (short)bfr(linW[k * 64 + n]);
    }
}

// ---------------- fused scatter phase: wave computes m for its own 16 nodes ----------------
// READS hin (bf16 h of previous layer); never aliases the kernel's WB target.

__device__ __forceinline__ void scat16(const uint4* __restrict__ hin,
                                       const int* __restrict__ off,
                                       const int2* __restrict__ cedge,
                                       int rbase, int l, short* mls) {
    int g = l >> 3;   // edge slot 0..7
    int f = l & 7;    // uint4 chunk within row
    for (int n = 0; n < 16; n++) {
        int node = rbase + n;
        int s = 0, e = 0;
        if (node < NN) { s = off[node]; e = off[node + 1]; }
        float a0 = 0.f, a1 = 0.f, a2 = 0.f, a3 = 0.f;
        float a4 = 0.f, a5 = 0.f, a6 = 0.f, a7 = 0.f;
        for (int i = s + g; i < e; i += 8) {
            int2 ed = cedge[i];
            uint4 hv = hin[(size_t)ed.x * 8 + f];
            float a = __int_as_float(ed.y);
            a0 += a * __uint_as_float(hv.x << 16);
            a1 += a * __uint_as_float(hv.x & 0xffff0000u);
            a2 += a * __uint_as_float(hv.y << 16);
            a3 += a * __uint_as_float(hv.y & 0xffff0000u);
            a4 += a * __uint_as_float(hv.z << 16);
            a5 += a * __uint_as_float(hv.z & 0xffff0000u);
            a6 += a * __uint_as_float(hv.w << 16);
            a7 += a * __uint_as_float(hv.w & 0xffff0000u);
        }
#pragma unroll
        for (int msk = 8; msk <= 32; msk <<= 1) {
            a0 += __shfl_xor(a0, msk);
            a1 += __shfl_xor(a1, msk);
            a2 += __shfl_xor(a2, msk);
            a3 += __shfl_xor(a3, msk);
            a4 += __shfl_xor(a4, msk);
            a5 += __shfl_xor(a5, msk);
            a6 += __shfl_xor(a6, msk);
            a7 += __shfl_xor(a7, msk);
        }
        if (g == 0) {
            uint4 o;
            o.x = bf2(a0, a1);
            o.y = bf2(a2, a3);
            o.z = bf2(a4, a5);
            o.w = bf2(a6, a7);
            *(uint4*)&mls[n * 72 + f * 8] = o;
        }
    }
}

// ---------------- MFMA conv core (one weight set) ----------------

__device__ __forceinline__ void conv_core(bf16x8 a0, bf16x8 a1,
                                          const bf16x8* __restrict__ w1f,
                                          const float* __restrict__ b1,
                                          const bf16x8* __restrict__ w2f,
                                          short* tw, int c, int q, int l,
                                          f32x4 oc[4]) {
    f32x4 acc[4];
#pragma unroll
    for (int t = 0; t < 4; t++) acc[t] = (f32x4){0.f, 0.f, 0.f, 0.f};
#pragma unroll
    for (int t = 0; t < 4; t++) {
        acc[t] = MFMA(a0, w1f[(t * 2 + 0) * 64 + l], acc[t]);
        acc[t] = MFMA(a1, w1f[(t * 2 + 1) * 64 + l], acc[t]);
    }
#pragma unroll
    for (int t = 0; t < 4; t++) {
        float bb = b1[16 * t + c];
#pragma unroll
        for (int rg = 0; rg < 4; rg++) {
            float v = fmaxf(acc[t][rg] + bb, 0.f);
            tw[(4 * q + rg) * 72 + 16 * t + c] = (short)bfr(v);
        }
    }
    __syncthreads();
    bf16x8 ta0 = *(const bf16x8*)&tw[c * 72 + 8 * q];
    bf16x8 ta1 = *(const bf16x8*)&tw[c * 72 + 32 + 8 * q];
#pragma unroll
    for (int t = 0; t < 4; t++) oc[t] = (f32x4){0.f, 0.f, 0.f, 0.f};
#pragma unroll
    for (int t = 0; t < 4; t++) {
        oc[t] = MFMA(ta0, w2f[(t * 2 + 0) * 64 + l], oc[t]);
        oc[t] = MFMA(ta1, w2f[(t * 2 + 1) * 64 + l], oc[t]);
    }
}

// ---------------- fused scatter + single conv ----------------
// out = [hprev +] relu(m@W1+b1)@W2+b2, m computed in-block from CSR.
// hin (gather source) and hbout (bf16 WB) are DISJOINT buffers (ping-pong)
// to avoid the cross-block read/write race.

template <bool ADD, bool WB>
__global__ __launch_bounds__(256) void fscm_k(const uint4* __restrict__ hin,
                                              const int* __restrict__ off,
                                              const int2* __restrict__ cedge,
                                              const short* __restrict__ w1p,
                                              const float* __restrict__ b1,
                                              const short* __restrict__ w2p,
                                              const float* __restrict__ b2,
                                              const float* __restrict__ hprev,
                                              float* __restrict__ out,
                                              unsigned int* __restrict__ hbout) {
    __shared__ short mls[4][16 * 72];
    __shared__ short tls[4][16 * 72];
    int wv = threadIdx.x >> 6, l = threadIdx.x & 63;
    int c = l & 15, q = l >> 4;
    int rbase = blockIdx.x * 64 + wv * 16;

    scat16(hin, off, cedge, rbase, l, mls[wv]);

    bf16x8 a0 = *(const bf16x8*)&mls[wv][c * 72 + 8 * q];
    bf16x8 a1 = *(const bf16x8*)&mls[wv][c * 72 + 32 + 8 * q];

    f32x4 oc[4];
    conv_core(a0, a1, (const bf16x8*)w1p, b1, (const bf16x8*)w2p, tls[wv], c, q, l, oc);

#pragma unroll
    for (int t = 0; t < 4; t++) {
        float bb = b2[16 * t + c];
#pragma unroll
        for (int rg = 0; rg < 4; rg++) {
            int row = rbase + 4 * q + rg;
            if (row < NN) {
                float v = oc[t][rg] + bb;
                if constexpr (ADD) v += hprev[(size_t)row * 64 + 16 * t + c];
                out[(size_t)row * 64 + 16 * t + c] = v;
                if constexpr (WB) {
                    float o = __shfl_xor(v, 1);
                    if ((c & 1) == 0)
                        hbout[(size_t)row * 32 + 8 * t + (c >> 1)] = bf2(v, o);
                }
            }
        }
    }
}

// ---------------- fused scatter + dual conv ----------------
// outa = conv_a(m); outb = hprev + conv_b(m) (+ bf16 WB of outb into hbout)

__global__ __launch_bounds__(256) void fsc2_k(const uint4* __restrict__ hin,
                                              const int* __restrict__ off,
                                              const int2* __restrict__ cedge,
                                              const short* __restrict__ wa1,
                                              const float* __restrict__ ba1,
                                              const short* __restrict__ wa2,
                                              const float* __restrict__ ba2,
                                              const short* __restrict__ wb1,
                                              const float* __restrict__ bb1,
                                              const short* __restrict__ wb2,
                                              const float* __restrict__ bb2,
                                              const float* __restrict__ hprev,
                                              float* __restrict__ outa,
                                              float* __restrict__ outb,
                                              unsigned int* __restrict__ hbout) {
    __shared__ short mls[4][16 * 72];
    __shared__ short tls[4][16 * 72];
    int wv = threadIdx.x >> 6, l = threadIdx.x & 63;
    int c = l & 15, q = l >> 4;
    int rbase = blockIdx.x * 64 + wv * 16;

    scat16(hin, off, cedge, rbase, l, mls[wv]);

    bf16x8 a0 = *(const bf16x8*)&mls[wv][c * 72 + 8 * q];
    bf16x8 a1 = *(const bf16x8*)&mls[wv][c * 72 + 32 + 8 * q];

    f32x4 oc[4];
    conv_core(a0, a1, (const bf16x8*)wa1, ba1, (const bf16x8*)wa2, tls[wv], c, q, l, oc);
#pragma unroll
    for (int t = 0; t < 4; t++) {
        float bb = ba2[16 * t + c];
#pragma unroll
        for (int rg = 0; rg < 4; rg++) {
            int row = rbase + 4 * q + rg;
            if (row < NN)
                outa[(size_t)row * 64 + 16 * t + c] = oc[t][rg] + bb;
        }
    }
    __syncthreads();  // tls reuse

    conv_core(a0, a1, (const bf16x8*)wb1, bb1, (const bf16x8*)wb2, tls[wv], c, q, l, oc);
#pragma unroll
    for (int t = 0; t < 4; t++) {
        float bb = bb2[16 * t + c];
#pragma unroll
        for (int rg = 0; rg < 4; rg++) {
            int row = rbase + 4 * q + rg;
            if (row < NN) {
                float v = oc[t][rg] + bb + hprev[(size_t)row * 64 + 16 * t + c];
                outb[(size_t)row * 64 + 16 * t + c] = v;
                float o = __shfl_xor(v, 1);
                if ((c & 1) == 0)
                    hbout[(size_t)row * 32 + 8 * t + (c >> 1)] = bf2(v, o);
            }
        }
    }
}

// ---------------- MFMA input linear: h0 = x @ lin_W + lin_b (+ bf16 copy) ----------------

__global__ __launch_bounds__(256) void linm_k(const float* __restrict__ x,
                                              const short* __restrict__ wp,
                                              const float* __restrict__ b,
                                              float* __restrict__ h0,
                                              unsigned int* __restrict__ hb) {
    int wv = threadIdx.x >> 6, l = threadIdx.x & 63;
    int c = l & 15, q = l >> 4;
    int rbase = blockIdx.x * 64 + wv * 16;
    int ar = rbase + c;
    bool aok = ar < NN;

    bf16x8 af[4];
#pragma unroll
    for (int s = 0; s < 4; s++) {
        float4 p0 = make_float4(0, 0, 0, 0), p1 = p0;
        if (aok) {
            const float4* xp = (const float4*)(x + (size_t)ar * FIN + 32 * s + 8 * q);
            p0 = xp[0];
            p1 = xp[1];
        }
        bf16x8 t;
        t[0] = (short)bfr(p0.x); t[1] = (short)bfr(p0.y);
        t[2] = (short)bfr(p0.z); t[3] = (short)bfr(p0.w);
        t[4] = (short)bfr(p1.x); t[5] = (short)bfr(p1.y);
        t[6] = (short)bfr(p1.z); t[7] = (short)bfr(p1.w);
        af[s] = t;
    }

    const bf16x8* wf = (const bf16x8*)wp;
    f32x4 acc[4];
#pragma unroll
    for (int t = 0; t < 4; t++) acc[t] = (f32x4){0.f, 0.f, 0.f, 0.f};
#pragma unroll
    for (int t = 0; t < 4; t++)
#pragma unroll
        for (int s = 0; s < 4; s++)
            acc[t] = MFMA(af[s], wf[(t * 4 + s) * 64 + l], acc[t]);

#pragma unroll
    for (int t = 0; t < 4; t++) {
        float bb = b[16 * t + c];
#pragma unroll
        for (int rg = 0; rg < 4; rg++) {
            int row = rbase + 4 * q + rg;
            if (row < NN) {
                float v = acc[t][rg] + bb;
                h0[(size_t)row * 64 + 16 * t + c] = v;
                float o = __shfl_xor(v, 1);
                if ((c & 1) == 0)
                    hb[(size_t)row * 32 + 8 * t + (c >> 1)] = bf2(v, o);
            }
        }
    }
}

// ---------------- launch ----------------

extern "C" void kernel_launch(void* const* d_in, const int* in_sizes, int n_in,
                              void* d_out, int out_size, void* d_ws, size_t ws_size,
                              hipStream_t stream) {
    (void)in_sizes; (void)n_in; (void)out_size; (void)ws_size;

    const float* x    = (const float*)d_in[0];
    const int*   ei   = (const int*)d_in[1];
    const float* attr = (const float*)d_in[2];
    const float* linW = (const float*)d_in[3];
    const float* linb = (const float*)d_in[4];
    const float* W1   = (const float*)d_in[5];
    const float* b1   = (const float*)d_in[6];
    const float* W2   = (const float*)d_in[7];
    const float* b2   = (const float*)d_in[8];
    float* out = (float*)d_out;

    // workspace (16B alignment at each boundary)
    float*        h0    = (float*)d_ws;                          // NN*64 f32 (12.8MB)
    unsigned int* hba   = (unsigned int*)(h0 + (size_t)NN * HD); // NN*32 (bf16 h, ping)
    unsigned int* hbb   = hba + (size_t)NN * 32;                 // NN*32 (bf16 h, pong)
    int2*         cedge = (int2*)(hbb + (size_t)NN * 32);        // NE (node-sorted)
    short*        prep  = (short*)(cedge + NE);                  // 32768 shorts
    int*          cnt   = (int*)(prep + 32768);                  // NN
    int*          off   = cnt + NN;                              // NN+1
    int*          cur   = off + NN + 1;                          // NN
    int*          parts = cur + NN;                              // 256
    int*          pscan = parts + 256;                           // 256
    int*          gbcur = pscan + 256;                           // 256
    int2*         tedge = (int2*)h0;  // ALIAS: h0 dead until linm_k (CSR build precedes it)

    const int* src = ei;
    const int* dst = ei + NE;

    float* scats = out;
    float* outs  = out + (size_t)SL * NN * HD;

    const size_t NH = (size_t)NN * HD;
    const int EB = (NE + 255) / 256;

    const short* w1p0 = prep;            // layer i: prep + i*8192
    const short* w2p0 = prep + 4096;
    const short* linp = prep + 24576;

    // per-node CSR build (binned two-phase fill)
    hipMemsetAsync(cnt, 0, NN * sizeof(int), stream);
    hist_k<<<EB, 256, 0, stream>>>(dst, cnt);
    partial_k<<<NBL, 256, 0, stream>>>(cnt, parts);
    scanp_k<<<1, 256, 0, stream>>>(parts, pscan, off);
    offs_k<<<NBL, 256, 0, stream>>>(cnt, pscan, off, cur);
    gbininit_k<<<1, 256, 0, stream>>>(off, gbcur);
    binpass_k<<<196, 256, 0, stream>>>(src, dst, attr, gbcur, tedge);
    sortbin_k<<<NB, 256, 0, stream>>>(off, tedge, cur, cedge);
    wprep_k<<<128, 256, 0, stream>>>(W1, W2, linW, prep);

    // h0 = x @ lin_W + lin_b (+ bf16 into hba)
    linm_k<<<GBM, 256, 0, stream>>>(x, linp, linb, h0, hba);

    // layer 0: outs0 = h0 + conv0(scatter(h0));  read hba, WB -> hbb
    fscm_k<true, true><<<GBM, 256, 0, stream>>>((const uint4*)hba, off, cedge,
                                                w1p0, b1, w2p0, b2, h0, outs, hbb);

    // scats0 (W0) + outs1 = outs0 + conv1;  read hbb, WB -> hba
    fsc2_k<<<GBM, 256, 0, stream>>>((const uint4*)hbb, off, cedge,
                                    w1p0, b1, w2p0, b2,
                                    w1p0 + 8192, b1 + 64, w2p0 + 8192, b2 + 64,
                                    outs, scats, outs + NH, hba);

    // scats1 (W1) + outs2 = outs1 + conv2;  read hba, WB -> hbb
    fsc2_k<<<GBM, 256, 0, stream>>>((const uint4*)hba, off, cedge,
                                    w1p0 + 8192, b1 + 64, w2p0 + 8192, b2 + 64,
                                    w1p0 + 16384, b1 + 128, w2p0 + 16384, b2 + 128,
                                    outs + NH, scats + NH, outs + 2 * NH, hbb);

    // scats2 (W2);  read hbb, no WB
    fscm_k<false, false><<<GBM, 256, 0, stream>>>((const uint4*)hbb, off, cedge,
                                                  w1p0 + 16384, b1 + 128,
                                                  w2p0 + 16384, b2 + 128,
                                                  nullptr, scats + 2 * NH, nullptr);
}

// Round 10
// 219.514 us; speedup vs baseline: 6.8598x; 1.3970x over previous
//
#include <hip/hip_runtime.h>

#define NN 50000
#define NE 800000
#define FIN 128
#define HD 64
#define SL 3
#define GBM 782    // ceil(NN/64) row-tiles for MFMA kernels
#define NBIN 196   // ceil(NN/256) dst bins
#define BSH 8      // 256 nodes per bin

typedef __attribute__((ext_vector_type(8))) short bf16x8;
typedef __attribute__((ext_vector_type(4))) float f32x4;
#define MFMA(A, B, C) __builtin_amdgcn_mfma_f32_16x16x32_bf16(A, B, C, 0, 0, 0)

// ---------------- bf16 pack helpers (RNE) ----------------

__device__ __forceinline__ unsigned int bfr(float x) {
    unsigned int u = __float_as_uint(x);
    return (u + 0x7fffu + ((u >> 16) & 1u)) >> 16;
}
__device__ __forceinline__ unsigned int bf2(float lo, float hi) {
    return bfr(lo) | (bfr(hi) << 16);
}

// ---------------- bin-level CSR build (no per-node global atomics) ----------------

// per-block LDS histogram of dst>>8; one global atomicAdd per (block,bin)
__global__ __launch_bounds__(256) void binhist_k(const int* __restrict__ dst,
                                                 int* __restrict__ bincnt) {
    __shared__ int h[256];
    int t = threadIdx.x;
    h[t] = 0;
    __syncthreads();
    int base = blockIdx.x * 4096;
    for (int i = t; i < 4096; i += 256) {
        int e = base + i;
        if (e < NE) atomicAdd(&h[dst[e] >> BSH], 1);
    }
    __syncthreads();
    if (t < NBIN && h[t]) atomicAdd(&bincnt[t], h[t]);
}

// exclusive scan of 196 bin counts -> binoff; seed gbcur; off[NN]=NE
__global__ __launch_bounds__(256) void binscan_k(const int* __restrict__ bincnt,
                                                 int* __restrict__ binoff,
                                                 int* __restrict__ gbcur,
                                                 int* __restrict__ off) {
    __shared__ int sh[256];
    int t = threadIdx.x;
    int v = (t < NBIN) ? bincnt[t] : 0;
    sh[t] = v;
    __syncthreads();
    for (int d = 1; d < 256; d <<= 1) {
        int u = (t >= d) ? sh[t - d] : 0;
        __syncthreads();
        sh[t] += u;
        __syncthreads();
    }
    if (t < NBIN) {
        int ex = sh[t] - v;
        binoff[t] = ex;
        gbcur[t] = ex;
    }
    if (t == 255) {
        binoff[NBIN] = sh[255];
        off[NN] = sh[255];   // == NE
    }
}

// partition edges into 196 dst-bin runs. packed: src (16b) | (dst & 255) << 16
__global__ __launch_bounds__(256) void binpass_k(const int* __restrict__ src,
                                                 const int* __restrict__ dst,
                                                 const float* __restrict__ attr,
                                                 int* __restrict__ gbcur,
                                                 int2* __restrict__ tedge) {
    __shared__ int cnt_lds[256], runbase[256], lcur[256];
    int t = threadIdx.x;
    cnt_lds[t] = 0;
    lcur[t] = 0;
    __syncthreads();
    int base = blockIdx.x * 4096;
    for (int i = t; i < 4096; i += 256) {
        int e = base + i;
        if (e < NE) atomicAdd(&cnt_lds[dst[e] >> BSH], 1);
    }
    __syncthreads();
    if (t < NBIN && cnt_lds[t]) runbase[t] = atomicAdd(&gbcur[t], cnt_lds[t]);
    __syncthreads();
    for (int i = t; i < 4096; i += 256) {
        int e = base + i;
        if (e < NE) {
            int d = dst[e];
            int b = d >> BSH;
            int r = atomicAdd(&lcur[b], 1);
            tedge[runbase[b] + r] =
                make_int2(src[e] | ((d & 255) << 16), __float_as_int(attr[e]));
        }
    }
}

// counting sort within each bin: derives per-node off[] in LDS (no global
// per-node atomics) and node-sorts edges within the bin's L2-resident window.
__global__ __launch_bounds__(256) void sortbin2_k(const int* __restrict__ binoff,
                                                  const int2* __restrict__ tedge,
                                                  int2* __restrict__ cedge,
                                                  int* __restrict__ off) {
    __shared__ int cnt[256], lofs[256], lcur[256];
    int b = blockIdx.x, t = threadIdx.x;
    int s = binoff[b], e = binoff[b + 1];
    cnt[t] = 0;
    __syncthreads();
    for (int i = s + t; i < e; i += 256)
        atomicAdd(&cnt[((unsigned)tedge[i].x >> 16) & 255], 1);
    __syncthreads();
    int v = cnt[t];
    lofs[t] = v;
    __syncthreads();
    for (int d = 1; d < 256; d <<= 1) {
        int u = (t >= d) ? lofs[t - d] : 0;
        __syncthreads();
        lofs[t] += u;
        __syncthreads();
    }
    int ex = lofs[t] - v;  // exclusive prefix within bin
    int node = (b << BSH) + t;
    if (node < NN) off[node] = s + ex;
    lcur[t] = ex;
    __syncthreads();
    for (int i = s + t; i < e; i += 256) {
        int2 ed = tedge[i];
        int dl = ((unsigned)ed.x >> 16) & 255;
        int p = s + atomicAdd(&lcur[dl], 1);
        cedge[p] = make_int2(ed.x & 0xffff, ed.y);
    }
}

// ---------------- weight prep: swizzle into MFMA B-fragment order, bf16 ----------------

__global__ __launch_bounds__(256) void wprep_k(const float* __restrict__ W1,
                                               const float* __restrict__ W2,
                                               const float* __restrict__ linW,
                                               short* __restrict__ prep) {
    int i = blockIdx.x * 256 + threadIdx.x;
    if (i < 24576) {
        int mat = i >> 12;
        int o = i & 4095;
        int j = o & 7, l = (o >> 3) & 63, s = (o >> 9) & 1, t = o >> 10;
        int k = 32 * s + 8 * (l >> 4) + j;
        int n = 16 * t + (l & 15);
        const float* Wsrc = (mat & 1) ? W2 : W1;
        prep[i] = (short)bfr(Wsrc[(mat >> 1) * 4096 + k * 64 + n]);
    } else if (i < 32768) {
        int o = i - 24576;
        int j = o & 7, l = (o >> 3) & 63, s = (o >> 9) & 3, t = o >> 11;
        int k = 32 * s + 8 * (l >> 4) + j;
        int n = 16 * t + (l & 15);
        prep[i] = (short)bfr(linW[k * 64 + n]);
    }
}

// ---------------- scatter: mb[n] = bf16( sum attr[e] * hb[src[e]] ) ----------------
// wave per dst node (max parallelism); 8 lanes per edge, shfl-xor tree reduce.

__global__ __launch_bounds__(256) void scatter_k(const uint4* __restrict__ hb4,
                                                 const int* __restrict__ off,
                                                 const int2* __restrict__ cedge,
                                                 uint4* __restrict__ mb4) {
    int w    = (blockIdx.x * blockDim.x + threadIdx.x) >> 6;
    int lane = threadIdx.x & 63;
    if (w >= NN) return;
    int g = lane >> 3;
    int f = lane & 7;
    int s = off[w], e = off[w + 1];
    float a0 = 0.f, a1 = 0.f, a2 = 0.f, a3 = 0.f;
    float a4 = 0.f, a5 = 0.f, a6 = 0.f, a7 = 0.f;
    for (int i = s + g; i < e; i += 8) {
        int2 ed = cedge[i];
        uint4 hv = hb4[(size_t)ed.x * 8 + f];
        float a = __int_as_float(ed.y);
        a0 += a * __uint_as_float(hv.x << 16);
        a1 += a * __uint_as_float(hv.x & 0xffff0000u);
        a2 += a * __uint_as_float(hv.y << 16);
        a3 += a * __uint_as_float(hv.y & 0xffff0000u);
        a4 += a * __uint_as_float(hv.z << 16);
        a5 += a * __uint_as_float(hv.z & 0xffff0000u);
        a6 += a * __uint_as_float(hv.w << 16);
        a7 += a * __uint_as_float(hv.w & 0xffff0000u);
    }
#pragma unroll
    for (int msk = 8; msk <= 32; msk <<= 1) {
        a0 += __shfl_xor(a0, msk);
        a1 += __shfl_xor(a1, msk);
        a2 += __shfl_xor(a2, msk);
        a3 += __shfl_xor(a3, msk);
        a4 += __shfl_xor(a4, msk);
        a5 += __shfl_xor(a5, msk);
        a6 += __shfl_xor(a6, msk);
        a7 += __shfl_xor(a7, msk);
    }
    if (g == 0) {
        uint4 o;
        o.x = bf2(a0, a1);
        o.y = bf2(a2, a3);
        o.z = bf2(a4, a5);
        o.w = bf2(a6, a7);
        mb4[(size_t)w * 8 + f] = o;
    }
}

// ---------------- MFMA conv core (one weight set) ----------------

__device__ __forceinline__ void conv_core(bf16x8 a0, bf16x8 a1,
                                          const bf16x8* __restrict__ w1f,
                                          const float* __restrict__ b1,
                                          const bf16x8* __restrict__ w2f,
                                          short* tw, int c, int q, int l,
                                          f32x4 oc[4]) {
    f32x4 acc[4];
#pragma unroll
    for (int t = 0; t < 4; t++) acc[t] = (f32x4){0.f, 0.f, 0.f, 0.f};
#pragma unroll
    for (int t = 0; t < 4; t++) {
        acc[t] = MFMA(a0, w1f[(t * 2 + 0) * 64 + l], acc[t]);
        acc[t] = MFMA(a1, w1f[(t * 2 + 1) * 64 + l], acc[t]);
    }
#pragma unroll
    for (int t = 0; t < 4; t++) {
        float bb = b1[16 * t + c];
#pragma unroll
        for (int rg = 0; rg < 4; rg++) {
            float v = fmaxf(acc[t][rg] + bb, 0.f);
            tw[(4 * q + rg) * 72 + 16 * t + c] = (short)bfr(v);
        }
    }
    __syncthreads();
    bf16x8 ta0 = *(const bf16x8*)&tw[c * 72 + 8 * q];
    bf16x8 ta1 = *(const bf16x8*)&tw[c * 72 + 32 + 8 * q];
#pragma unroll
    for (int t = 0; t < 4; t++) oc[t] = (f32x4){0.f, 0.f, 0.f, 0.f};
#pragma unroll
    for (int t = 0; t < 4; t++) {
        oc[t] = MFMA(ta0, w2f[(t * 2 + 0) * 64 + l], oc[t]);
        oc[t] = MFMA(ta1, w2f[(t * 2 + 1) * 64 + l], oc[t]);
    }
}

// ---------------- single conv: out = [hprev +] relu(m@W1+b1)@W2+b2 ----------------

template <bool ADD, bool WB>
__global__ __launch_bounds__(256) void convm_k(const unsigned int* __restrict__ mb,
                                               const short* __restrict__ w1p,
                                               const float* __restrict__ b1,
                                               const short* __restrict__ w2p,
                                               const float* __restrict__ b2,
                                               const float* __restrict__ hprev,
                                               float* __restrict__ out,
                                               unsigned int* __restrict__ hb) {
    __shared__ short tls[4][16 * 72];
    int wv = threadIdx.x >> 6, l = threadIdx.x & 63;
    int c = l & 15, q = l >> 4;
    int rbase = blockIdx.x * 64 + wv * 16;

    int ar = rbase + c;
    bool aok = ar < NN;
    uint4 v0 = make_uint4(0, 0, 0, 0), v1 = v0;
    if (aok) {
        const uint4* mp = (const uint4*)(mb + (size_t)ar * 32);
        v0 = mp[q];
        v1 = mp[4 + q];
    }
    bf16x8 a0 = *(bf16x8*)&v0, a1 = *(bf16x8*)&v1;

    f32x4 oc[4];
    conv_core(a0, a1, (const bf16x8*)w1p, b1, (const bf16x8*)w2p, tls[wv], c, q, l, oc);

#pragma unroll
    for (int t = 0; t < 4; t++) {
        float bb = b2[16 * t + c];
#pragma unroll
        for (int rg = 0; rg < 4; rg++) {
            int row = rbase + 4 * q + rg;
            if (row < NN) {
                float v = oc[t][rg] + bb;
                if constexpr (ADD) v += hprev[(size_t)row * 64 + 16 * t + c];
                out[(size_t)row * 64 + 16 * t + c] = v;
                if constexpr (WB) {
                    float o = __shfl_xor(v, 1);
                    if ((c & 1) == 0)
                        hb[(size_t)row * 32 + 8 * t + (c >> 1)] = bf2(v, o);
                }
            }
        }
    }
}

// ---------------- dual conv: outa = conv_a(m); outb = hprev + conv_b(m) (+bf16 WB) ----------------

__global__ __launch_bounds__(256) void conv2_k(const unsigned int* __restrict__ mb,
                                               const short* __restrict__ wa1,
                                               const float* __restrict__ ba1,
                                               const short* __restrict__ wa2,
                                               const float* __restrict__ ba2,
                                               const short* __restrict__ wb1,
                                               const float* __restrict__ bb1,
                                               const short* __restrict__ wb2,
                                               const float* __restrict__ bb2,
                                               const float* __restrict__ hprev,
                                               float* __restrict__ outa,
                                               float* __restrict__ outb,
                                               unsigned int* __restrict__ hb) {
    __shared__ short tls[4][16 * 72];
    int wv = threadIdx.x >> 6, l = threadIdx.x & 63;
    int c = l & 15, q = l >> 4;
    int rbase = blockIdx.x * 64 + wv * 16;

    int ar = rbase + c;
    bool aok = ar < NN;
    uint4 v0 = make_uint4(0, 0, 0, 0), v1 = v0;
    if (aok) {
        const uint4* mp = (const uint4*)(mb + (size_t)ar * 32);
        v0 = mp[q];
        v1 = mp[4 + q];
    }
    bf16x8 a0 = *(bf16x8*)&v0, a1 = *(bf16x8*)&v1;

    f32x4 oc[4];
    conv_core(a0, a1, (const bf16x8*)wa1, ba1, (const bf16x8*)wa2, tls[wv], c, q, l, oc);
#pragma unroll
    for (int t = 0; t < 4; t++) {
        float bb = ba2[16 * t + c];
#pragma unroll
        for (int rg = 0; rg < 4; rg++) {
            int row = rbase + 4 * q + rg;
            if (row < NN)
                outa[(size_t)row * 64 + 16 * t + c] = oc[t][rg] + bb;
        }
    }
    __syncthreads();  // tls reuse

    conv_core(a0, a1, (const bf16x8*)wb1, bb1, (const bf16x8*)wb2, tls[wv], c, q, l, oc);
#pragma unroll
    for (int t = 0; t < 4; t++) {
        float bb = bb2[16 * t + c];
#pragma unroll
        for (int rg = 0; rg < 4; rg++) {
            int row = rbase + 4 * q + rg;
            if (row < NN) {
                float v = oc[t][rg] + bb + hprev[(size_t)row * 64 + 16 * t + c];
                outb[(size_t)row * 64 + 16 * t + c] = v;
                float o = __shfl_xor(v, 1);
                if ((c & 1) == 0)
                    hb[(size_t)row * 32 + 8 * t + (c >> 1)] = bf2(v, o);
            }
        }
    }
}

// ---------------- MFMA input linear: h0 = x @ lin_W + lin_b (+ bf16 copy) ----------------

__global__ __launch_bounds__(256) void linm_k(const float* __restrict__ x,
                                              const short* __restrict__ wp,
                                              const float* __restrict__ b,
                                              float* __restrict__ h0,
                                              unsigned int* __restrict__ hb) {
    int wv = threadIdx.x >> 6, l = threadIdx.x & 63;
    int c = l & 15, q = l >> 4;
    int rbase = blockIdx.x * 64 + wv * 16;
    int ar = rbase + c;
    bool aok = ar < NN;

    bf16x8 af[4];
#pragma unroll
    for (int s = 0; s < 4; s++) {
        float4 p0 = make_float4(0, 0, 0, 0), p1 = p0;
        if (aok) {
            const float4* xp = (const float4*)(x + (size_t)ar * FIN + 32 * s + 8 * q);
            p0 = xp[0];
            p1 = xp[1];
        }
        bf16x8 t;
        t[0] = (short)bfr(p0.x); t[1] = (short)bfr(p0.y);
        t[2] = (short)bfr(p0.z); t[3] = (short)bfr(p0.w);
        t[4] = (short)bfr(p1.x); t[5] = (short)bfr(p1.y);
        t[6] = (short)bfr(p1.z); t[7] = (short)bfr(p1.w);
        af[s] = t;
    }

    const bf16x8* wf = (const bf16x8*)wp;
    f32x4 acc[4];
#pragma unroll
    for (int t = 0; t < 4; t++) acc[t] = (f32x4){0.f, 0.f, 0.f, 0.f};
#pragma unroll
    for (int t = 0; t < 4; t++)
#pragma unroll
        for (int s = 0; s < 4; s++)
            acc[t] = MFMA(af[s], wf[(t * 4 + s) * 64 + l], acc[t]);

#pragma unroll
    for (int t = 0; t < 4; t++) {
        float bb = b[16 * t + c];
#pragma unroll
        for (int rg = 0; rg < 4; rg++) {
            int row = rbase + 4 * q + rg;
            if (row < NN) {
                float v = acc[t][rg] + bb;
                h0[(size_t)row * 64 + 16 * t + c] = v;
                float o = __shfl_xor(v, 1);
                if ((c & 1) == 0)
                    hb[(size_t)row * 32 + 8 * t + (c >> 1)] = bf2(v, o);
            }
        }
    }
}

// ---------------- launch ----------------

extern "C" void kernel_launch(void* const* d_in, const int* in_sizes, int n_in,
                              void* d_out, int out_size, void* d_ws, size_t ws_size,
                              hipStream_t stream) {
    (void)in_sizes; (void)n_in; (void)out_size; (void)ws_size;

    const float* x    = (const float*)d_in[0];
    const int*   ei   = (const int*)d_in[1];
    const float* attr = (const float*)d_in[2];
    const float* linW = (const float*)d_in[3];
    const float* linb = (const float*)d_in[4];
    const float* W1   = (const float*)d_in[5];
    const float* b1   = (const float*)d_in[6];
    const float* W2   = (const float*)d_in[7];
    const float* b2   = (const float*)d_in[8];
    float* out = (float*)d_out;

    // workspace (16B alignment at each boundary)
    float*        h0     = (float*)d_ws;                          // NN*64 f32
    unsigned int* mb     = (unsigned int*)(h0 + (size_t)NN * HD); // NN*32 (bf16 m)
    unsigned int* hb     = mb + (size_t)NN * 32;                  // NN*32 (bf16 h)
    int2*         cedge  = (int2*)(hb + (size_t)NN * 32);         // NE (node-sorted)
    short*        prep   = (short*)(cedge + NE);                  // 32768 shorts
    int*          off    = (int*)(prep + 32768);                  // NN+1
    int*          bincnt = off + NN + 1;                          // 256
    int*          binoff = bincnt + 256;                          // 256+1
    int*          gbcur  = binoff + 257;                          // 256
    int2*         tedge  = (int2*)h0;  // ALIAS: h0 dead until linm_k

    const int* src = ei;
    const int* dst = ei + NE;

    float* scats = out;
    float* outs  = out + (size_t)SL * NN * HD;

    const size_t NH = (size_t)NN * HD;
    const int WB_ = (NN * 64) / 256;

    const short* w1p0 = prep;            // layer i: prep + i*8192
    const short* w2p0 = prep + 4096;
    const short* linp = prep + 24576;

    // bin-level CSR build (4 kernels, no per-node global atomics)
    hipMemsetAsync(bincnt, 0, 256 * sizeof(int), stream);
    binhist_k<<<196, 256, 0, stream>>>(dst, bincnt);
    binscan_k<<<1, 256, 0, stream>>>(bincnt, binoff, gbcur, off);
    binpass_k<<<196, 256, 0, stream>>>(src, dst, attr, gbcur, tedge);
    sortbin2_k<<<NBIN, 256, 0, stream>>>(binoff, tedge, cedge, off);
    wprep_k<<<128, 256, 0, stream>>>(W1, W2, linW, prep);

    // h0 = x @ lin_W + lin_b (+ bf16 into hb)
    linm_k<<<GBM, 256, 0, stream>>>(x, linp, linb, h0, hb);

    // layer 0
    scatter_k<<<WB_, 256, 0, stream>>>((const uint4*)hb, off, cedge, (uint4*)mb);
    convm_k<true, true><<<GBM, 256, 0, stream>>>(mb, w1p0, b1, w2p0, b2, h0, outs, hb);

    // scatter(outs0): scats0 (W0) + outs1 (W1) fused
    scatter_k<<<WB_, 256, 0, stream>>>((const uint4*)hb, off, cedge, (uint4*)mb);
    conv2_k<<<GBM, 256, 0, stream>>>(mb, w1p0, b1, w2p0, b2,
                                     w1p0 + 8192, b1 + 64, w2p0 + 8192, b2 + 64,
                                     outs, scats, outs + NH, hb);

    // scatter(outs1): scats1 (W1) + outs2 (W2) fused
    scatter_k<<<WB_, 256, 0, stream>>>((const uint4*)hb, off, cedge, (uint4*)mb);
    conv2_k<<<GBM, 256, 0, stream>>>(mb, w1p0 + 8192, b1 + 64, w2p0 + 8192, b2 + 64,
                                     w1p0 + 16384, b1 + 128, w2p0 + 16384, b2 + 128,
                                     outs + NH, scats + NH, outs + 2 * NH, hb);

    // scatter(outs2): scats2 (W2)
    scatter_k<<<WB_, 256, 0, stream>>>((const uint4*)hb, off, cedge, (uint4*)mb);
    convm_k<false, false><<<GBM, 256, 0, stream>>>(mb, w1p0 + 16384, b1 + 128,
                                                   w2p0 + 16384, b2 + 128,
                                                   nullptr, scats + 2 * NH, nullptr);
}

// Round 11
// 209.159 us; speedup vs baseline: 7.1994x; 1.0495x over previous
//
#include <hip/hip_runtime.h>

#define NN 50000
#define NE 800000
#define FIN 128
#define HD 64
#define SL 3
#define GBM 782    // ceil(NN/64) row-tiles for MFMA kernels
#define NBIN 196   // ceil(NN/256) dst bins
#define BSH 8      // 256 nodes per bin
#define CAP 8064   // per-bin tedge capacity (mean 4082, ~62 sigma headroom)

typedef __attribute__((ext_vector_type(8))) short bf16x8;
typedef __attribute__((ext_vector_type(4))) float f32x4;
#define MFMA(A, B, C) __builtin_amdgcn_mfma_f32_16x16x32_bf16(A, B, C, 0, 0, 0)

// ---------------- bf16 pack helpers (RNE) ----------------

__device__ __forceinline__ unsigned int bfr(float x) {
    unsigned int u = __float_as_uint(x);
    return (u + 0x7fffu + ((u >> 16) & 1u)) >> 16;
}
__device__ __forceinline__ unsigned int bf2(float lo, float hi) {
    return bfr(lo) | (bfr(hi) << 16);
}

// ---------------- CSR build: zero -> strided binpass -> binscan -> sortbin2 ----------------

// replaces hipMemsetAsync (captured fillBufferAligned cost ~47 us/replay!)
__global__ void zero_k(int* __restrict__ g) {
    if (threadIdx.x < NBIN) g[threadIdx.x] = 0;
}

// partition edges into per-bin STRIDED runs (tedge[b*CAP + ...]); gcur counts.
// packed: src (16b) | (dst & 255) << 16
__global__ __launch_bounds__(256) void binpass_k(const int* __restrict__ src,
                                                 const int* __restrict__ dst,
                                                 const float* __restrict__ attr,
                                                 int* __restrict__ gcur,
                                                 int2* __restrict__ tedge) {
    __shared__ int cnt_lds[256], runbase[256], lcur[256];
    int t = threadIdx.x;
    cnt_lds[t] = 0;
    lcur[t] = 0;
    __syncthreads();
    int base = blockIdx.x * 4096;
    for (int i = t; i < 4096; i += 256) {
        int e = base + i;
        if (e < NE) atomicAdd(&cnt_lds[dst[e] >> BSH], 1);
    }
    __syncthreads();
    if (t < NBIN && cnt_lds[t]) runbase[t] = atomicAdd(&gcur[t], cnt_lds[t]);
    __syncthreads();
    for (int i = t; i < 4096; i += 256) {
        int e = base + i;
        if (e < NE) {
            int d = dst[e];
            int b = d >> BSH;
            int r = atomicAdd(&lcur[b], 1);
            tedge[(size_t)b * CAP + runbase[b] + r] =
                make_int2(src[e] | ((d & 255) << 16), __float_as_int(attr[e]));
        }
    }
}

// exclusive scan of final gcur counts -> binoff; off[NN]=NE
__global__ __launch_bounds__(256) void binscan_k(const int* __restrict__ gcur,
                                                 int* __restrict__ binoff,
                                                 int* __restrict__ off) {
    __shared__ int sh[256];
    int t = threadIdx.x;
    int v = (t < NBIN) ? gcur[t] : 0;
    sh[t] = v;
    __syncthreads();
    for (int d = 1; d < 256; d <<= 1) {
        int u = (t >= d) ? sh[t - d] : 0;
        __syncthreads();
        sh[t] += u;
        __syncthreads();
    }
    if (t < NBIN) binoff[t] = sh[t] - v;
    if (t == 255) {
        binoff[NBIN] = sh[255];
        off[NN] = sh[255];   // == NE
    }
}

// per-bin counting sort: strided tedge -> compact node-sorted cedge; derives off[].
__global__ __launch_bounds__(256) void sortbin2_k(const int* __restrict__ binoff,
                                                  const int2* __restrict__ tedge,
                                                  int2* __restrict__ cedge,
                                                  int* __restrict__ off) {
    __shared__ int cnt[256], lofs[256], lcur[256];
    int b = blockIdx.x, t = threadIdx.x;
    int s = binoff[b];
    int n_in_bin = binoff[b + 1] - s;
    const int2* tb = tedge + (size_t)b * CAP;
    cnt[t] = 0;
    __syncthreads();
    for (int i = t; i < n_in_bin; i += 256)
        atomicAdd(&cnt[((unsigned)tb[i].x >> 16) & 255], 1);
    __syncthreads();
    int v = cnt[t];
    lofs[t] = v;
    __syncthreads();
    for (int d = 1; d < 256; d <<= 1) {
        int u = (t >= d) ? lofs[t - d] : 0;
        __syncthreads();
        lofs[t] += u;
        __syncthreads();
    }
    int ex = lofs[t] - v;  // exclusive prefix within bin
    int node = (b << BSH) + t;
    if (node < NN) off[node] = s + ex;
    lcur[t] = ex;
    __syncthreads();
    for (int i = t; i < n_in_bin; i += 256) {
        int2 ed = tb[i];
        int dl = ((unsigned)ed.x >> 16) & 255;
        int p = s + atomicAdd(&lcur[dl], 1);
        cedge[p] = make_int2(ed.x & 0xffff, ed.y);
    }
}

// ---------------- weight prep: swizzle into MFMA B-fragment order, bf16 ----------------

__global__ __launch_bounds__(256) void wprep_k(const float* __restrict__ W1,
                                               const float* __restrict__ W2,
                                               const float* __restrict__ linW,
                                               short* __restrict__ prep) {
    int i = blockIdx.x * 256 + threadIdx.x;
    if (i < 24576) {
        int mat = i >> 12;
        int o = i & 4095;
        int j = o & 7, l = (o >> 3) & 63, s = (o >> 9) & 1, t = o >> 10;
        int k = 32 * s + 8 * (l >> 4) + j;
        int n = 16 * t + (l & 15);
        const float* Wsrc = (mat & 1) ? W2 : W1;
        prep[i] = (short)bfr(Wsrc[(mat >> 1) * 4096 + k * 64 + n]);
    } else if (i < 32768) {
        int o = i - 24576;
        int j = o & 7, l = (o >> 3) & 63, s = (o >> 9) & 3, t = o >> 11;
        int k = 32 * s + 8 * (l >> 4) + j;
        int n = 16 * t + (l & 15);
        prep[i] = (short)bfr(linW[k * 64 + n]);
    }
}

// ---------------- scatter: mb[n] = bf16( sum attr[e] * hb[src[e]] ) ----------------
// wave per dst node; 8 lanes per edge, shfl-xor tree reduce. No atomics.

__global__ __launch_bounds__(256) void scatter_k(const uint4* __restrict__ hb4,
                                                 const int* __restrict__ off,
                                                 const int2* __restrict__ cedge,
                                                 uint4* __restrict__ mb4) {
    int w    = (blockIdx.x * blockDim.x + threadIdx.x) >> 6;
    int lane = threadIdx.x & 63;
    if (w >= NN) return;
    int g = lane >> 3;
    int f = lane & 7;
    int s = off[w], e = off[w + 1];
    float a0 = 0.f, a1 = 0.f, a2 = 0.f, a3 = 0.f;
    float a4 = 0.f, a5 = 0.f, a6 = 0.f, a7 = 0.f;
    for (int i = s + g; i < e; i += 8) {
        int2 ed = cedge[i];
        uint4 hv = hb4[(size_t)ed.x * 8 + f];
        float a = __int_as_float(ed.y);
        a0 += a * __uint_as_float(hv.x << 16);
        a1 += a * __uint_as_float(hv.x & 0xffff0000u);
        a2 += a * __uint_as_float(hv.y << 16);
        a3 += a * __uint_as_float(hv.y & 0xffff0000u);
        a4 += a * __uint_as_float(hv.z << 16);
        a5 += a * __uint_as_float(hv.z & 0xffff0000u);
        a6 += a * __uint_as_float(hv.w << 16);
        a7 += a * __uint_as_float(hv.w & 0xffff0000u);
    }
#pragma unroll
    for (int msk = 8; msk <= 32; msk <<= 1) {
        a0 += __shfl_xor(a0, msk);
        a1 += __shfl_xor(a1, msk);
        a2 += __shfl_xor(a2, msk);
        a3 += __shfl_xor(a3, msk);
        a4 += __shfl_xor(a4, msk);
        a5 += __shfl_xor(a5, msk);
        a6 += __shfl_xor(a6, msk);
        a7 += __shfl_xor(a7, msk);
    }
    if (g == 0) {
        uint4 o;
        o.x = bf2(a0, a1);
        o.y = bf2(a2, a3);
        o.z = bf2(a4, a5);
        o.w = bf2(a6, a7);
        mb4[(size_t)w * 8 + f] = o;
    }
}

// ---------------- MFMA conv core (one weight set) ----------------

__device__ __forceinline__ void conv_core(bf16x8 a0, bf16x8 a1,
                                          const bf16x8* __restrict__ w1f,
                                          const float* __restrict__ b1,
                                          const bf16x8* __restrict__ w2f,
                                          short* tw, int c, int q, int l,
                                          f32x4 oc[4]) {
    f32x4 acc[4];
#pragma unroll
    for (int t = 0; t < 4; t++) acc[t] = (f32x4){0.f, 0.f, 0.f, 0.f};
#pragma unroll
    for (int t = 0; t < 4; t++) {
        acc[t] = MFMA(a0, w1f[(t * 2 + 0) * 64 + l], acc[t]);
        acc[t] = MFMA(a1, w1f[(t * 2 + 1) * 64 + l], acc[t]);
    }
#pragma unroll
    for (int t = 0; t < 4; t++) {
        float bb = b1[16 * t + c];
#pragma unroll
        for (int rg = 0; rg < 4; rg++) {
            float v = fmaxf(acc[t][rg] + bb, 0.f);
            tw[(4 * q + rg) * 72 + 16 * t + c] = (short)bfr(v);
        }
    }
    __syncthreads();
    bf16x8 ta0 = *(const bf16x8*)&tw[c * 72 + 8 * q];
    bf16x8 ta1 = *(const bf16x8*)&tw[c * 72 + 32 + 8 * q];
#pragma unroll
    for (int t = 0; t < 4; t++) oc[t] = (f32x4){0.f, 0.f, 0.f, 0.f};
#pragma unroll
    for (int t = 0; t < 4; t++) {
        oc[t] = MFMA(ta0, w2f[(t * 2 + 0) * 64 + l], oc[t]);
        oc[t] = MFMA(ta1, w2f[(t * 2 + 1) * 64 + l], oc[t]);
    }
}

// ---------------- single conv: out = [hprev +] relu(m@W1+b1)@W2+b2 ----------------

template <bool ADD, bool WB>
__global__ __launch_bounds__(256) void convm_k(const unsigned int* __restrict__ mb,
                                               const short* __restrict__ w1p,
                                               const float* __restrict__ b1,
                                               const short* __restrict__ w2p,
                                               const float* __restrict__ b2,
                                               const float* __restrict__ hprev,
                                               float* __restrict__ out,
                                               unsigned int* __restrict__ hb) {
    __shared__ short tls[4][16 * 72];
    int wv = threadIdx.x >> 6, l = threadIdx.x & 63;
    int c = l & 15, q = l >> 4;
    int rbase = blockIdx.x * 64 + wv * 16;

    int ar = rbase + c;
    bool aok = ar < NN;
    uint4 v0 = make_uint4(0, 0, 0, 0), v1 = v0;
    if (aok) {
        const uint4* mp = (const uint4*)(mb + (size_t)ar * 32);
        v0 = mp[q];
        v1 = mp[4 + q];
    }
    bf16x8 a0 = *(bf16x8*)&v0, a1 = *(bf16x8*)&v1;

    f32x4 oc[4];
    conv_core(a0, a1, (const bf16x8*)w1p, b1, (const bf16x8*)w2p, tls[wv], c, q, l, oc);

#pragma unroll
    for (int t = 0; t < 4; t++) {
        float bb = b2[16 * t + c];
#pragma unroll
        for (int rg = 0; rg < 4; rg++) {
            int row = rbase + 4 * q + rg;
            if (row < NN) {
                float v = oc[t][rg] + bb;
                if constexpr (ADD) v += hprev[(size_t)row * 64 + 16 * t + c];
                out[(size_t)row * 64 + 16 * t + c] = v;
                if constexpr (WB) {
                    float o = __shfl_xor(v, 1);
                    if ((c & 1) == 0)
                        hb[(size_t)row * 32 + 8 * t + (c >> 1)] = bf2(v, o);
                }
            }
        }
    }
}

// ---------------- dual conv: outa = conv_a(m); outb = hprev + conv_b(m) (+bf16 WB) ----------------

__global__ __launch_bounds__(256) void conv2_k(const unsigned int* __restrict__ mb,
                                               const short* __restrict__ wa1,
                                               const float* __restrict__ ba1,
                                               const short* __restrict__ wa2,
                                               const float* __restrict__ ba2,
                                               const short* __restrict__ wb1,
                                               const float* __restrict__ bb1,
                                               const short* __restrict__ wb2,
                                               const float* __restrict__ bb2,
                                               const float* __restrict__ hprev,
                                               float* __restrict__ outa,
                                               float* __restrict__ outb,
                                               unsigned int* __restrict__ hb) {
    __shared__ short tls[4][16 * 72];
    int wv = threadIdx.x >> 6, l = threadIdx.x & 63;
    int c = l & 15, q = l >> 4;
    int rbase = blockIdx.x * 64 + wv * 16;

    int ar = rbase + c;
    bool aok = ar < NN;
    uint4 v0 = make_uint4(0, 0, 0, 0), v1 = v0;
    if (aok) {
        const uint4* mp = (const uint4*)(mb + (size_t)ar * 32);
        v0 = mp[q];
        v1 = mp[4 + q];
    }
    bf16x8 a0 = *(bf16x8*)&v0, a1 = *(bf16x8*)&v1;

    f32x4 oc[4];
    conv_core(a0, a1, (const bf16x8*)wa1, ba1, (const bf16x8*)wa2, tls[wv], c, q, l, oc);
#pragma unroll
    for (int t = 0; t < 4; t++) {
        float bb = ba2[16 * t + c];
#pragma unroll
        for (int rg = 0; rg < 4; rg++) {
            int row = rbase + 4 * q + rg;
            if (row < NN)
                outa[(size_t)row * 64 + 16 * t + c] = oc[t][rg] + bb;
        }
    }
    __syncthreads();  // tls reuse

    conv_core(a0, a1, (const bf16x8*)wb1, bb1, (const bf16x8*)wb2, tls[wv], c, q, l, oc);
#pragma unroll
    for (int t = 0; t < 4; t++) {
        float bb = bb2[16 * t + c];
#pragma unroll
        for (int rg = 0; rg < 4; rg++) {
            int row = rbase + 4 * q + rg;
            if (row < NN) {
                float v = oc[t][rg] + bb + hprev[(size_t)row * 64 + 16 * t + c];
                outb[(size_t)row * 64 + 16 * t + c] = v;
                float o = __shfl_xor(v, 1);
                if ((c & 1) == 0)
                    hb[(size_t)row * 32 + 8 * t + (c >> 1)] = bf2(v, o);
            }
        }
    }
}

// ---------------- MFMA input linear: h0 = x @ lin_W + lin_b (+ bf16 copy) ----------------

__global__ __launch_bounds__(256) void linm_k(const float* __restrict__ x,
                                              const short* __restrict__ wp,
                                              const float* __restrict__ b,
                                              float* __restrict__ h0,
                                              unsigned int* __restrict__ hb) {
    int wv = threadIdx.x >> 6, l = threadIdx.x & 63;
    int c = l & 15, q = l >> 4;
    int rbase = blockIdx.x * 64 + wv * 16;
    int ar = rbase + c;
    bool aok = ar < NN;

    bf16x8 af[4];
#pragma unroll
    for (int s = 0; s < 4; s++) {
        float4 p0 = make_float4(0, 0, 0, 0), p1 = p0;
        if (aok) {
            const float4* xp = (const float4*)(x + (size_t)ar * FIN + 32 * s + 8 * q);
            p0 = xp[0];
            p1 = xp[1];
        }
        bf16x8 t;
        t[0] = (short)bfr(p0.x); t[1] = (short)bfr(p0.y);
        t[2] = (short)bfr(p0.z); t[3] = (short)bfr(p0.w);
        t[4] = (short)bfr(p1.x); t[5] = (short)bfr(p1.y);
        t[6] = (short)bfr(p1.z); t[7] = (short)bfr(p1.w);
        af[s] = t;
    }

    const bf16x8* wf = (const bf16x8*)wp;
    f32x4 acc[4];
#pragma unroll
    for (int t = 0; t < 4; t++) acc[t] = (f32x4){0.f, 0.f, 0.f, 0.f};
#pragma unroll
    for (int t = 0; t < 4; t++)
#pragma unroll
        for (int s = 0; s < 4; s++)
            acc[t] = MFMA(af[s], wf[(t * 4 + s) * 64 + l], acc[t]);

#pragma unroll
    for (int t = 0; t < 4; t++) {
        float bb = b[16 * t + c];
#pragma unroll
        for (int rg = 0; rg < 4; rg++) {
            int row = rbase + 4 * q + rg;
            if (row < NN) {
                float v = acc[t][rg] + bb;
                h0[(size_t)row * 64 + 16 * t + c] = v;
                float o = __shfl_xor(v, 1);
                if ((c & 1) == 0)
                    hb[(size_t)row * 32 + 8 * t + (c >> 1)] = bf2(v, o);
            }
        }
    }
}

// ---------------- launch ----------------

extern "C" void kernel_launch(void* const* d_in, const int* in_sizes, int n_in,
                              void* d_out, int out_size, void* d_ws, size_t ws_size,
                              hipStream_t stream) {
    (void)in_sizes; (void)n_in; (void)out_size; (void)ws_size;

    const float* x    = (const float*)d_in[0];
    const int*   ei   = (const int*)d_in[1];
    const float* attr = (const float*)d_in[2];
    const float* linW = (const float*)d_in[3];
    const float* linb = (const float*)d_in[4];
    const float* W1   = (const float*)d_in[5];
    const float* b1   = (const float*)d_in[6];
    const float* W2   = (const float*)d_in[7];
    const float* b2   = (const float*)d_in[8];
    float* out = (float*)d_out;

    // workspace (16B alignment at each boundary)
    float*        h0     = (float*)d_ws;                          // NN*64 f32 (12.8MB)
    unsigned int* mb     = (unsigned int*)(h0 + (size_t)NN * HD); // NN*32 (bf16 m)
    unsigned int* hb     = mb + (size_t)NN * 32;                  // NN*32 (bf16 h)
    int2*         cedge  = (int2*)(hb + (size_t)NN * 32);         // NE (node-sorted)
    short*        prep   = (short*)(cedge + NE);                  // 32768 shorts
    int*          off    = (int*)(prep + 32768);                  // NN+1
    int*          gcur   = off + NN + 1;                          // 256 (bin counts)
    int*          binoff = gcur + 256;                            // 256+1
    int2*         tedge  = (int2*)h0;  // ALIAS: 196*CAP*8B = 12.64MB <= 12.8MB; h0 dead until linm_k

    const int* src = ei;
    const int* dst = ei + NE;

    float* scats = out;
    float* outs  = out + (size_t)SL * NN * HD;

    const size_t NH = (size_t)NN * HD;
    const int WB_ = (NN * 64) / 256;

    const short* w1p0 = prep;            // layer i: prep + i*8192
    const short* w2p0 = prep + 4096;
    const short* linp = prep + 24576;

    // CSR build: zero -> strided binpass (counts in gcur) -> binscan -> sortbin2
    zero_k<<<1, 256, 0, stream>>>(gcur);
    binpass_k<<<196, 256, 0, stream>>>(src, dst, attr, gcur, tedge);
    binscan_k<<<1, 256, 0, stream>>>(gcur, binoff, off);
    sortbin2_k<<<NBIN, 256, 0, stream>>>(binoff, tedge, cedge, off);
    wprep_k<<<128, 256, 0, stream>>>(W1, W2, linW, prep);

    // h0 = x @ lin_W + lin_b (+ bf16 into hb)
    linm_k<<<GBM, 256, 0, stream>>>(x, linp, linb, h0, hb);

    // layer 0
    scatter_k<<<WB_, 256, 0, stream>>>((const uint4*)hb, off, cedge, (uint4*)mb);
    convm_k<true, true><<<GBM, 256, 0, stream>>>(mb, w1p0, b1, w2p0, b2, h0, outs, hb);

    // scatter(outs0): scats0 (W0) + outs1 (W1) fused
    scatter_k<<<WB_, 256, 0, stream>>>((const uint4*)hb, off, cedge, (uint4*)mb);
    conv2_k<<<GBM, 256, 0, stream>>>(mb, w1p0, b1, w2p0, b2,
                                     w1p0 + 8192, b1 + 64, w2p0 + 8192, b2 + 64,
                                     outs, scats, outs + NH, hb);

    // scatter(outs1): scats1 (W1) + outs2 (W2) fused
    scatter_k<<<WB_, 256, 0, stream>>>((const uint4*)hb, off, cedge, (uint4*)mb);
    conv2_k<<<GBM, 256, 0, stream>>>(mb, w1p0 + 8192, b1 + 64, w2p0 + 8192, b2 + 64,
                                     w1p0 + 16384, b1 + 128, w2p0 + 16384, b2 + 128,
                                     outs + NH, scats + NH, outs + 2 * NH, hb);

    // scatter(outs2): scats2 (W2)
    scatter_k<<<WB_, 256, 0, stream>>>((const uint4*)hb, off, cedge, (uint4*)mb);
    convm_k<false, false><<<GBM, 256, 0, stream>>>(mb, w1p0 + 16384, b1 + 128,
                                                   w2p0 + 16384, b2 + 128,
                                                   nullptr, scats + 2 * NH, nullptr);
}